// Round 10
// baseline (201.474 us; speedup 1.0000x reference)
//
#include <hip/hip_runtime.h>

// Involution2d: B=8, C=256, G=4 (Cpg=64), H=W=Ho=Wo=64, K=7, PAD=3, STRIDE=1.
// out[b, g*64+c, y, x] = sum_{kh,kw} in[b, g*64+c, y+kh-3, x+kw-3] * w[b,g,kh,kw,y,x] + bias[g*64+c]
//
// Round-10 = round-6 (best, 47.5us dispatch) + XCD-clustered dispatch.
// r9 lesson: raising the occupancy CAP doesn't raise residency (33% both) ->
// TLP is fixed; must cut per-wave stall. The dominant stall is the weight
// stream: each weight f4 is read by 16 blocks (64ch / NC=4). With bx-inner
// grid order, those 16 sharers scatter round-robin across the 8 XCDs ->
// every XCD re-fetches the tile from L3 (~400-900cyc loads). Here: 1D grid,
// id = xcd + 8*by + 128*(t/8) with t = bx + 4*bz, xcd = t%8 -> all 16
// sharers (by=0..15) land on ONE XCD as consecutive dispatches -> weight
// tile (200KB) stays in that XCD's 4MB L2 -> ~200cyc hits.
// Also: bias folded into acc init (r9's one good micro-change).
// LDS: r6's stride-24 + XOR swizzle kept (8.8M conflict cycles, best
// measured; r9's stride-18 "zero waste" was WORSE at 15.1M -> reverted).

#define BLK_X 16
#define BLK_Y 16
#define NTHR  256
#define NC    4
#define ROWS  16                  // output rows per block (= BLK_Y)
#define S_ROWS 22                 // ROWS + 6 halo
#define ST_F4 24                  // float4 stride per staged row (mult of 8)
#define S_CH_F4 (S_ROWS * ST_F4)  // 528 float4 per channel
#define SEGS (S_ROWS * 18)        // 396 valid float4 per channel

// load 7 weight float4 for kernel row KH into buf (coalesced dwordx4)
#define LOADW(buf, KH) do {                                                 \
    _Pragma("unroll")                                                       \
    for (int kw_ = 0; kw_ < 7; ++kw_)                                       \
        buf[kw_] = *(const float4*)(wb + (size_t)((KH) * 7 + kw_) * 4096);  \
} while (0)

// one kh step: 4 channels x (3 swizzled b128 reads + 28 FMAs) with weights W
#define STEP(KH, W) do {                                                    \
    const int row_ = ty + (KH);          /* staged row 0..21 */             \
    const int xm_  = row_ & 7;                                              \
    _Pragma("unroll")                                                       \
    for (int ch_ = 0; ch_ < NC; ++ch_) {                                    \
        const float4* lp_ = lds4 + ch_ * S_CH_F4 + row_ * ST_F4;            \
        float4 v0_ = lp_[(tx + 0) ^ xm_];                                   \
        float4 v1_ = lp_[(tx + 1) ^ xm_];                                   \
        float4 v2_ = lp_[(tx + 2) ^ xm_];                                   \
        float vals_[12] = {v0_.x, v0_.y, v0_.z, v0_.w,                      \
                           v1_.x, v1_.y, v1_.z, v1_.w,                      \
                           v2_.x, v2_.y, v2_.z, v2_.w};                     \
        _Pragma("unroll")                                                   \
        for (int kw_ = 0; kw_ < 7; ++kw_) {                                 \
            acc[ch_][0] += vals_[kw_ + 1] * W[kw_].x;                       \
            acc[ch_][1] += vals_[kw_ + 2] * W[kw_].y;                       \
            acc[ch_][2] += vals_[kw_ + 3] * W[kw_].z;                       \
            acc[ch_][3] += vals_[kw_ + 4] * W[kw_].w;                       \
        }                                                                   \
    }                                                                       \
} while (0)

__global__ __launch_bounds__(NTHR, 4)
void involution_kernel(const float* __restrict__ in,
                       const float* __restrict__ w,
                       const float* __restrict__ bias,
                       float* __restrict__ out) {
    __shared__ float4 lds4[NC * S_CH_F4];   // 33,792 B -> 4 blocks/CU

    const int tx  = threadIdx.x;            // 0..15 (x-quad)
    const int ty  = threadIdx.y;            // 0..15 (row)
    const int tid = ty * BLK_X + tx;        // 0..255

    // ---- XCD-clustered decode: id = xcd + 8*by + 128*(t>>3), t = bx+4*bz,
    //      xcd = t&7. The 16 by-sharers of a (bx,bz) tile are consecutive
    //      dispatches on one XCD -> weight tile L2-resident there.
    const int id  = blockIdx.x;             // 0..2047
    const int xcd = id & 7;
    const int by  = (id >> 3) & 15;         // channel tile
    const int t   = ((id >> 7) << 3) | xcd; // 0..127
    const int bx  = t & 3;                  // y tile
    const int bz  = t >> 2;                 // b*4 + g

    const int x0  = tx * 4;
    const int Y0  = bx * ROWS;
    const int y   = Y0 + ty;
    const int c0  = by * NC;
    const int g   = bz & 3;

    const float* inb  = in  + (size_t)bz * 64 * 4096;
    float*       outb = out + (size_t)bz * 64 * 4096;
    const float* wb   = w   + (size_t)bz * 49 * 4096 + y * 64 + x0;

    float4 wA[7], wB[7];
    LOADW(wA, 0);                 // kh=0 weights hide under staging

    // ---- stage NC channels once, swizzled, single barrier ----
    // cols t=0..17; halo t=0/17 stays zero; data t=1..16 maps to gx=4(t-1);
    // slot = row*24 + (t ^ (row&7)).
    #pragma unroll
    for (int ch = 0; ch < NC; ++ch) {
        const float* p = inb + (size_t)(c0 + ch) * 4096;
        #pragma unroll
        for (int j = 0; j < 2; ++j) {
            int e = tid + j * NTHR;          // 0..511, guard < 396
            if (e < SEGS) {
                int row = e / 18;
                int tt  = e - row * 18;
                int gy  = Y0 + row - 3;
                float4 v = make_float4(0.f, 0.f, 0.f, 0.f);
                if (tt >= 1 && tt <= 16 && gy >= 0 && gy < 64)
                    v = *(const float4*)(p + gy * 64 + (tt - 1) * 4);
                lds4[ch * S_CH_F4 + row * ST_F4 + (tt ^ (row & 7))] = v;
            }
        }
    }

    // bias folded into accumulator init
    float acc[NC][4];
    #pragma unroll
    for (int c = 0; c < NC; ++c) {
        const float bv = bias[g * 64 + c0 + c];
        acc[c][0] = bv; acc[c][1] = bv; acc[c][2] = bv; acc[c][3] = bv;
    }

    LOADW(wB, 1);                 // kh=1 weights hide under the barrier
    __syncthreads();

    // ---- depth-2 software-pipelined kh ladder (r6 structure, no pins) ----
    STEP(0, wA);  LOADW(wA, 2);
    STEP(1, wB);  LOADW(wB, 3);
    STEP(2, wA);  LOADW(wA, 4);
    STEP(3, wB);  LOADW(wB, 5);
    STEP(4, wA);  LOADW(wA, 6);
    STEP(5, wB);
    STEP(6, wA);

    // ---- epilogue (bias already accumulated) ----
    #pragma unroll
    for (int c = 0; c < NC; ++c) {
        float4 o;
        o.x = acc[c][0]; o.y = acc[c][1]; o.z = acc[c][2]; o.w = acc[c][3];
        *(float4*)(outb + (size_t)(c0 + c) * 4096 + y * 64 + x0) = o;
    }
}

extern "C" void kernel_launch(void* const* d_in, const int* in_sizes, int n_in,
                              void* d_out, int out_size, void* d_ws, size_t ws_size,
                              hipStream_t stream) {
    const float* in   = (const float*)d_in[0];  // (8,256,64,64)
    const float* wgt  = (const float*)d_in[1];  // (8,4,7,7,64,64)
    const float* bias = (const float*)d_in[2];  // (256,)
    float* out = (float*)d_out;                 // (8,256,64,64)

    dim3 block(BLK_X, BLK_Y, 1);                 // 256 threads = 4 waves
    dim3 grid(2048, 1, 1);                       // 1D, decoded in-kernel
    involution_kernel<<<grid, block, 0, stream>>>(in, wgt, bias, out);
}

// Round 11
// 149.174 us; speedup vs baseline: 1.3506x; 1.3506x over previous
//
#include <hip/hip_runtime.h>

// Involution2d: B=8, C=256, G=4 (Cpg=64), H=W=Ho=Wo=64, K=7, PAD=3, STRIDE=1.
// out[b, g*64+c, y, x] = sum_{kh,kw} in[b, g*64+c, y+kh-3, x+kw-3] * w[b,g,kh,kw,y,x] + bias[g*64+c]
//
// Round-11: async-DMA weight pipeline. Ten rounds proved this toolchain will
// not keep long-latency loads ahead of use in VGPRs (sinks r1/r2/r6/r8,
// spills r3/r5/r7/r10, remats r0) — so the weight stream moves OUT of the
// wave's instruction stream via __builtin_amdgcn_global_load_lds:
//  - per kh, the block's weight slab [7][128]xf4 (14.3KB) is DMA'd to LDS:
//    lane l deposits w[bz,kh,kw,y(l),x0(l)] at wave-uniform base + l*16
//    (exactly the HW contract). No VGPR round-trip, vmcnt-tracked, cannot
//    be "sunk to use" — the consumer is LDS after a barrier.
//  - slab ping-pong, ONE barrier per STEP: the compiler's vmcnt(0) drain
//    before s_barrier IS the DMA-completion sync; the ~650cyc STEP body
//    (224 FMA + 19 ds_read) hides the L2 fetch of the next slab.
//  - weight read-back: wv[kw] = wslab[buf][kw][tid] -> 7x ds_read_b128,
//    bank group = tid&7, uniform over 64 lanes -> conflict-free.
//  - register demand ~70: the 64-VGPR grant regime is now harmless —
//    nothing long-latency lives in registers.
// Input: r6's proven stride-24 + XOR-swizzle LDS, staged once (register
// path: needs zero-fill halo, so no DMA there). 128thr/NC=4/ROWS=8; LDS
// 50,176B -> 3 blocks/CU. Occupancy WILL read ~18% — by design.
// Decisive readouts: dur <= 30us, WRITE_SIZE == 32768KB, VALUBusy >= 40.

#define BLK_X 16
#define BLK_Y 8
#define NTHR  128
#define NC    4
#define ROWS  8                   // output rows per block (= BLK_Y)
#define S_ROWS 14                 // ROWS + 6 halo
#define ST_F4 24                  // float4 stride per staged row (mult of 8)
#define S_CH_F4 (S_ROWS * ST_F4)  // 336 float4 per channel
#define SEGS (S_ROWS * 18)        // 252 valid float4 per channel

// async-DMA one kh weight slab into wslab[BUF]: lane l of wave wid deposits
// its own (y,x0) weight f4 for kw at [kw][wid*64 + l]. LDS base is
// wave-uniform; global address is per-lane. vmcnt-tracked.
#define ISSUE_SLAB(BUF, KH) do {                                            \
    _Pragma("unroll")                                                       \
    for (int kw_ = 0; kw_ < 7; ++kw_) {                                     \
        __builtin_amdgcn_global_load_lds(                                   \
            (const __attribute__((address_space(1))) void*)                 \
                (wb + (size_t)((KH) * 7 + kw_) * 4096),                     \
            (__attribute__((address_space(3))) void*)                       \
                (&wslab[BUF][kw_][wid << 6]),                               \
            16, 0, 0);                                                      \
    }                                                                       \
} while (0)

// one kh step: read 7 weight f4 from slab BUF (conflict-free), then
// 4 channels x (3 swizzled b128 input reads + 28 FMAs)
#define STEP(KH, BUF) do {                                                  \
    float4 wv_[7];                                                          \
    _Pragma("unroll")                                                       \
    for (int kw_ = 0; kw_ < 7; ++kw_)                                       \
        wv_[kw_] = wslab[BUF][kw_][tid];                                    \
    const int row_ = ty + (KH);          /* staged row 0..13 */             \
    const int xm_  = row_ & 7;                                              \
    _Pragma("unroll")                                                       \
    for (int ch_ = 0; ch_ < NC; ++ch_) {                                    \
        const float4* lp_ = lds4 + ch_ * S_CH_F4 + row_ * ST_F4;            \
        float4 v0_ = lp_[(tx + 0) ^ xm_];                                   \
        float4 v1_ = lp_[(tx + 1) ^ xm_];                                   \
        float4 v2_ = lp_[(tx + 2) ^ xm_];                                   \
        float vals_[12] = {v0_.x, v0_.y, v0_.z, v0_.w,                      \
                           v1_.x, v1_.y, v1_.z, v1_.w,                      \
                           v2_.x, v2_.y, v2_.z, v2_.w};                     \
        _Pragma("unroll")                                                   \
        for (int kw_ = 0; kw_ < 7; ++kw_) {                                 \
            acc[ch_][0] += vals_[kw_ + 1] * wv_[kw_].x;                     \
            acc[ch_][1] += vals_[kw_ + 2] * wv_[kw_].y;                     \
            acc[ch_][2] += vals_[kw_ + 3] * wv_[kw_].z;                     \
            acc[ch_][3] += vals_[kw_ + 4] * wv_[kw_].w;                     \
        }                                                                   \
    }                                                                       \
} while (0)

__global__ __launch_bounds__(NTHR)
void involution_kernel(const float* __restrict__ in,
                       const float* __restrict__ w,
                       const float* __restrict__ bias,
                       float* __restrict__ out) {
    __shared__ float4 lds4[NC * S_CH_F4];   // 21,504 B input (swizzled)
    __shared__ float4 wslab[2][7][NTHR];    // 28,672 B weight slab ping-pong

    const int tx  = threadIdx.x;            // 0..15 (x-quad)
    const int ty  = threadIdx.y;            // 0..7  (row)
    const int tid = ty * BLK_X + tx;        // 0..127
    const int wid = tid >> 6;               // wave 0..1
    const int x0  = tx * 4;
    const int Y0  = blockIdx.x * ROWS;
    const int y   = Y0 + ty;
    const int c0  = blockIdx.y * NC;
    const int bz  = blockIdx.z;             // b*4 + g
    const int g   = bz & 3;

    const float* inb  = in  + (size_t)bz * 64 * 4096;
    float*       outb = out + (size_t)bz * 64 * 4096;
    const float* wb   = w   + (size_t)bz * 49 * 4096 + y * 64 + x0;

    ISSUE_SLAB(0, 0);             // kh=0 slab DMAs during input staging

    // ---- stage NC input channels once, swizzled (r6 layout) ----
    // cols t=0..17; halo t=0/17 zero; data t=1..16 -> gx=4(t-1);
    // slot = row*24 + (t ^ (row&7)).
    #pragma unroll
    for (int ch = 0; ch < NC; ++ch) {
        const float* p = inb + (size_t)(c0 + ch) * 4096;
        #pragma unroll
        for (int j = 0; j < 2; ++j) {
            int e = tid + j * NTHR;          // 0..255, guard < 252
            if (e < SEGS) {
                int row = e / 18;
                int tt  = e - row * 18;
                int gy  = Y0 + row - 3;
                float4 v = make_float4(0.f, 0.f, 0.f, 0.f);
                if (tt >= 1 && tt <= 16 && gy >= 0 && gy < 64)
                    v = *(const float4*)(p + gy * 64 + (tt - 1) * 4);
                lds4[ch * S_CH_F4 + row * ST_F4 + (tt ^ (row & 7))] = v;
            }
        }
    }

    // bias folded into accumulator init
    float acc[NC][4];
    #pragma unroll
    for (int c = 0; c < NC; ++c) {
        const float bv = bias[g * 64 + c0 + c];
        acc[c][0] = bv; acc[c][1] = bv; acc[c][2] = bv; acc[c][3] = bv;
    }

    __syncthreads();              // slab0 landed + input visible

    // ---- DMA-pipelined kh ladder: issue slab k+1, compute slab k,
    //      barrier (vmcnt drain = slab k+1 ready; lgkm drain = reads done,
    //      so next issue may overwrite the other buffer). 8 barriers total.
    ISSUE_SLAB(1, 1);  STEP(0, 0);  __syncthreads();
    ISSUE_SLAB(0, 2);  STEP(1, 1);  __syncthreads();
    ISSUE_SLAB(1, 3);  STEP(2, 0);  __syncthreads();
    ISSUE_SLAB(0, 4);  STEP(3, 1);  __syncthreads();
    ISSUE_SLAB(1, 5);  STEP(4, 0);  __syncthreads();
    ISSUE_SLAB(0, 6);  STEP(5, 1);  __syncthreads();
    STEP(6, 0);

    // ---- epilogue (bias already accumulated) ----
    #pragma unroll
    for (int c = 0; c < NC; ++c) {
        float4 o;
        o.x = acc[c][0]; o.y = acc[c][1]; o.z = acc[c][2]; o.w = acc[c][3];
        *(float4*)(outb + (size_t)(c0 + c) * 4096 + y * 64 + x0) = o;
    }
}

extern "C" void kernel_launch(void* const* d_in, const int* in_sizes, int n_in,
                              void* d_out, int out_size, void* d_ws, size_t ws_size,
                              hipStream_t stream) {
    const float* in   = (const float*)d_in[0];  // (8,256,64,64)
    const float* wgt  = (const float*)d_in[1];  // (8,4,7,7,64,64)
    const float* bias = (const float*)d_in[2];  // (256,)
    float* out = (float*)d_out;                 // (8,256,64,64)

    dim3 block(BLK_X, BLK_Y, 1);                 // 128 threads = 2 waves
    dim3 grid(64 / ROWS, 64 / NC, 32);           // (8, 16, 32) = 4096 blocks
    involution_kernel<<<grid, block, 0, stream>>>(in, wgt, bias, out);
}